// Round 8
// baseline (669.318 us; speedup 1.0000x reference)
//
#include <hip/hip_runtime.h>
#include <hip/hip_bf16.h>

// Problem constants (B=1)
#define S_LEN 2048
#define HID 2048
#define NH 16
#define HD 256
#define NROT 64
#define NOPE 192
#define QL 1024
#define OR_ 512
#define NG 4
#define HPG 4
#define EPS 1e-6f
#define SCALE 0.0625f   // 256^-0.5

typedef __bf16 bf16x8 __attribute__((ext_vector_type(8)));
typedef short s16x8 __attribute__((ext_vector_type(8)));
typedef float f32x4 __attribute__((ext_vector_type(4)));

#define MFMA(a, b, c) __builtin_amdgcn_mfma_f32_16x16x32_bf16( \
    __builtin_bit_cast(bf16x8, a), __builtin_bit_cast(bf16x8, b), c, 0, 0, 0)

__device__ __forceinline__ unsigned short f2bf(float x) {
  unsigned int u = __builtin_bit_cast(unsigned int, x);
  u += 0x7FFFu + ((u >> 16) & 1u);   // RNE
  return (unsigned short)(u >> 16);
}
__device__ __forceinline__ float bf2f(unsigned short b) {
  unsigned int u = ((unsigned int)b) << 16;
  return __builtin_bit_cast(float, u);
}

// ---------------- fp32 -> bf16 convert (vectorized) ----------------
__global__ __launch_bounds__(256) void f32_to_bf16(const float* __restrict__ in,
                                                   unsigned short* __restrict__ out, int n4) {
  int i = blockIdx.x * 256 + threadIdx.x;
  if (i < n4) {
    float4 v = ((const float4*)in)[i];
    ushort4 o;
    o.x = f2bf(v.x); o.y = f2bf(v.y); o.z = f2bf(v.z); o.w = f2bf(v.w);
    ((ushort4*)out)[i] = o;
  }
}

// ---------------- bf16 MFMA GEMM: C[M,N] = A[M,K] @ B[N,K]^T ----------------
__global__ __launch_bounds__(256, 2) void gemm_bf16(
    const unsigned short* __restrict__ A, const unsigned short* __restrict__ B,
    void* __restrict__ Cv, int K, int lda, int ldb, int ldc,
    long aoffz, long boffz, long coffz, int store_bf) {
  __shared__ __align__(16) unsigned short As[128 * 40];
  __shared__ __align__(16) unsigned short Bs[128 * 40];
  A += (size_t)blockIdx.z * aoffz;
  B += (size_t)blockIdx.z * boffz;
  const int tid = threadIdx.x;
  const int wave = tid >> 6, lane = tid & 63;
  const int col = lane & 15, grp = lane >> 4;
  const int wm = wave >> 1, wn = wave & 1;
  const int m0 = blockIdx.y * 128, n0 = blockIdx.x * 128;

  f32x4 acc[4][4];
#pragma unroll
  for (int i = 0; i < 4; ++i)
#pragma unroll
    for (int j = 0; j < 4; ++j) acc[i][j] = (f32x4){0.f, 0.f, 0.f, 0.f};

  for (int k0 = 0; k0 < K; k0 += 32) {
#pragma unroll
    for (int u = 0; u < 2; ++u) {
      int lin = u * 256 + tid;
      int r = lin >> 2, c8 = (lin & 3) * 8;
      *(s16x8*)&As[r * 40 + c8] = *(const s16x8*)(A + (size_t)(m0 + r) * lda + k0 + c8);
      *(s16x8*)&Bs[r * 40 + c8] = *(const s16x8*)(B + (size_t)(n0 + r) * ldb + k0 + c8);
    }
    __syncthreads();
    s16x8 a[4], b[4];
#pragma unroll
    for (int i = 0; i < 4; ++i)
      a[i] = *(const s16x8*)&As[(wm * 64 + i * 16 + col) * 40 + grp * 8];
#pragma unroll
    for (int j = 0; j < 4; ++j)
      b[j] = *(const s16x8*)&Bs[(wn * 64 + j * 16 + col) * 40 + grp * 8];
#pragma unroll
    for (int i = 0; i < 4; ++i)
#pragma unroll
      for (int j = 0; j < 4; ++j)
        acc[i][j] = MFMA(a[i], b[j], acc[i][j]);
    __syncthreads();
  }

  if (store_bf) {
    unsigned short* C = (unsigned short*)Cv + (size_t)blockIdx.z * coffz;
#pragma unroll
    for (int i = 0; i < 4; ++i)
#pragma unroll
      for (int j = 0; j < 4; ++j)
#pragma unroll
        for (int r = 0; r < 4; ++r)
          C[(size_t)(m0 + wm * 64 + i * 16 + grp * 4 + r) * ldc +
            n0 + wn * 64 + j * 16 + col] = f2bf(acc[i][j][r]);
  } else {
    float* C = (float*)Cv + (size_t)blockIdx.z * coffz;
#pragma unroll
    for (int i = 0; i < 4; ++i)
#pragma unroll
      for (int j = 0; j < 4; ++j)
#pragma unroll
        for (int r = 0; r < 4; ++r)
          C[(size_t)(m0 + wm * 64 + i * 16 + grp * 4 + r) * ldc +
            n0 + wn * 64 + j * 16 + col] = acc[i][j][r];
  }
}

// ---------------- RMSNorm (weighted) in-place on bf16 rows of length L ----------------
__global__ __launch_bounds__(256) void rmsnorm_bf_ip(unsigned short* __restrict__ x,
                                                     const float* __restrict__ w, int L) {
  int row = blockIdx.x;
  unsigned short* p = x + (size_t)row * L;
  __shared__ float red[256];
  float s = 0.f;
  for (int i = threadIdx.x; i < L; i += 256) { float v = bf2f(p[i]); s += v * v; }
  red[threadIdx.x] = s;
  __syncthreads();
  for (int off = 128; off > 0; off >>= 1) {
    if (threadIdx.x < off) red[threadIdx.x] += red[threadIdx.x + off];
    __syncthreads();
  }
  float r = rsqrtf(red[0] / (float)L + EPS);
  for (int i = threadIdx.x; i < L; i += 256) p[i] = f2bf(bf2f(p[i]) * r * w[i]);
}

// ---------------- Q per-head RMS (no weight) + RoPE, in-place bf16 ----------------
__global__ __launch_bounds__(256) void qnorm_rope_ip(unsigned short* __restrict__ q,
                                                     const float* __restrict__ freqs) {
  int row = blockIdx.x;       // s*NH + h
  int s = row / NH;
  unsigned short* p = q + (size_t)row * HD;
  int d = threadIdx.x;
  float v = bf2f(p[d]);
  __shared__ float red[256];
  __shared__ float sm[256];
  red[d] = v * v;
  __syncthreads();
  for (int off = 128; off > 0; off >>= 1) {
    if (d < off) red[d] += red[d + off];
    __syncthreads();
  }
  float r = rsqrtf(red[0] / 256.0f + EPS);
  float nv = v * r;
  sm[d] = nv;
  __syncthreads();
  float outv = nv;
  if (d >= NOPE) {
    int j = (d - NOPE) >> 1;
    float f = freqs[(size_t)s * (NROT / 2) + j];
    float c = cosf(f), si = sinf(f);
    float x1 = sm[NOPE + 2 * j], x2 = sm[NOPE + 2 * j + 1];
    outv = ((d & 1) == 0) ? (x1 * c - x2 * si) : (x1 * si + x2 * c);
  }
  p[d] = f2bf(outv);
}

// ---------------- KV RMS (weighted) + RoPE, in-place bf16 + kvT global ----------------
__global__ __launch_bounds__(256) void kvnorm_rope_ip(unsigned short* __restrict__ kv,
                                                      const float* __restrict__ w,
                                                      const float* __restrict__ freqs,
                                                      unsigned short* __restrict__ kvT) {
  int s = blockIdx.x;
  unsigned short* p = kv + (size_t)s * HD;
  int d = threadIdx.x;
  float v = bf2f(p[d]);
  __shared__ float red[256];
  __shared__ float sm[256];
  red[d] = v * v;
  __syncthreads();
  for (int off = 128; off > 0; off >>= 1) {
    if (d < off) red[d] += red[d + off];
    __syncthreads();
  }
  float r = rsqrtf(red[0] / 256.0f + EPS);
  float nv = v * r * w[d];
  sm[d] = nv;
  __syncthreads();
  float outv = nv;
  if (d >= NOPE) {
    int j = (d - NOPE) >> 1;
    float f = freqs[(size_t)s * (NROT / 2) + j];
    float c = cosf(f), si = sinf(f);
    float x1 = sm[NOPE + 2 * j], x2 = sm[NOPE + 2 * j + 1];
    outv = ((d & 1) == 0) ? (x1 * c - x2 * si) : (x1 * si + x2 * c);
  }
  unsigned short ov = f2bf(outv);
  p[d] = ov;
  kvT[(size_t)d * S_LEN + s] = ov;   // transposed copy for PV B-frags
}

// ---------------- MFMA flash attention v3 ----------------
// Q in named regs; QK s-partition (wave owns 16 rows); PV d-partition (wave
// owns 64 d-cols: 4 pf + 4 vf loads, vf DIRECT FROM GLOBAL kvT — no reuse
// within block so LDS staging gains nothing). alpha/inv cross-wave via tiny
// LDS arrays (broadcast reads). LDS 23 KB. NO addressable arrays (R7 lesson).
__global__ __launch_bounds__(256, 3) void attn_mfma(
    const unsigned short* __restrict__ qbf,   // (S, NH*HD) bf16
    const unsigned short* __restrict__ kvbf,  // (S, HD) bf16
    const unsigned short* __restrict__ kvT,   // (HD, S) bf16
    const float* __restrict__ sink,
    const float* __restrict__ freqs,
    unsigned short* __restrict__ ob) {        // (S, NH*HD) bf16
  __shared__ __align__(16) unsigned short kv_s[32 * 264];  // [t][d]
  __shared__ __align__(16) unsigned short p_s[64 * 40];    // [row][t]
  __shared__ float alpha_s[64];
  __shared__ float inv_s[64];

  const int tid = threadIdx.x;
  const int wave = tid >> 6, lane = tid & 63;
  const int col = lane & 15, grp = lane >> 4;
  const int q0 = (gridDim.x - 1 - blockIdx.x) * 64;   // big tiles first (LPT)
  const int h = blockIdx.y;
  const int qrow = q0 + wave * 16;

  // Q fragments: 8 named s16x8 regs (32 VGPRs)
  const unsigned short* qbase =
      qbf + (size_t)(qrow + col) * (NH * HD) + (size_t)h * HD + grp * 8;
#define QDECL(ko, nam) s16x8 nam = *(const s16x8*)(qbase + (ko) * 32);
  QDECL(0, qf0) QDECL(1, qf1) QDECL(2, qf2) QDECL(3, qf3)
  QDECL(4, qf4) QDECL(5, qf5) QDECL(6, qf6) QDECL(7, qf7)

  const f32x4 z4 = (f32x4){0.f, 0.f, 0.f, 0.f};
  float m0r = -1e30f, m1r = -1e30f, m2r = -1e30f, m3r = -1e30f;
  float l0r = 0.f, l1r = 0.f, l2r = 0.f, l3r = 0.f;

#define FOR16(M) M(0,0,o00) M(0,1,o01) M(0,2,o02) M(0,3,o03) \
                 M(1,0,o10) M(1,1,o11) M(1,2,o12) M(1,3,o13) \
                 M(2,0,o20) M(2,1,o21) M(2,2,o22) M(2,3,o23) \
                 M(3,0,o30) M(3,1,o31) M(3,2,o32) M(3,3,o33)
#define DECLO(i, j, onam) f32x4 onam = z4;
  FOR16(DECLO)

#define STAGE(T0) { \
    _Pragma("unroll") \
    for (int rep = 0; rep < 4; ++rep) { \
      int u = rep * 256 + tid; \
      int t = u >> 5, dd = (u & 31) * 8; \
      *(s16x8*)&kv_s[t * 264 + dd] = \
          *(const s16x8*)(kvbf + (size_t)((T0) + t) * HD + dd); \
    } }

  STAGE(0)
  const int nch = q0 / 32 + 2;
  for (int ch = 0; ch < nch; ++ch) {
    const int t0 = ch * 32;
    __syncthreads();   // kv_s(ch) ready; p_s/alpha_s(ch-1) fully consumed

    // ---- QK^T ----
    f32x4 s0 = z4, s1 = z4;
#define QKS(ko, qf) { \
      s16x8 b0 = *(const s16x8*)&kv_s[col * 264 + (ko) * 32 + grp * 8]; \
      s16x8 b1 = *(const s16x8*)&kv_s[(16 + col) * 264 + (ko) * 32 + grp * 8]; \
      s0 = MFMA(qf, b0, s0); s1 = MFMA(qf, b1, s1); }
    QKS(0, qf0) QKS(1, qf1) QKS(2, qf2) QKS(3, qf3)
    QKS(4, qf4) QKS(5, qf5) QKS(6, qf6) QKS(7, qf7)

    // ---- scale + causal mask ----
#define MASKR(r) { int sg = qrow + grp * 4 + (r); \
    s0[r] = (t0 + col <= sg) ? s0[r] * SCALE : -1e30f; \
    s1[r] = (t0 + 16 + col <= sg) ? s1[r] * SCALE : -1e30f; }
    MASKR(0) MASKR(1) MASKR(2) MASKR(3)

    // ---- online softmax ----
    float a0, a1, a2, a3;
#define MAXR(r, mr, ar) { float v = fmaxf(s0[r], s1[r]); \
    v = fmaxf(v, __shfl_xor(v, 1)); v = fmaxf(v, __shfl_xor(v, 2)); \
    v = fmaxf(v, __shfl_xor(v, 4)); v = fmaxf(v, __shfl_xor(v, 8)); \
    float mn = fmaxf(mr, v); ar = __expf(mr - mn); mr = mn; }
    MAXR(0, m0r, a0) MAXR(1, m1r, a1) MAXR(2, m2r, a2) MAXR(3, m3r, a3)

    float rs0, rs1, rs2, rs3;
#define PROW(r, mr, rsr) { float p0 = __expf(s0[r] - mr); float p1 = __expf(s1[r] - mr); \
    rsr = p0 + p1; \
    p_s[(wave * 16 + grp * 4 + (r)) * 40 + col] = f2bf(p0); \
    p_s[(wave * 16 + grp * 4 + (r)) * 40 + 16 + col] = f2bf(p1); }
    PROW(0, m0r, rs0) PROW(1, m1r, rs1) PROW(2, m2r, rs2) PROW(3, m3r, rs3)

#define SUMR(r, rsr, lr, ar) { float v = rsr; \
    v += __shfl_xor(v, 1); v += __shfl_xor(v, 2); \
    v += __shfl_xor(v, 4); v += __shfl_xor(v, 8); \
    lr = lr * ar + v; }
    SUMR(0, rs0, l0r, a0) SUMR(1, rs1, l1r, a1) SUMR(2, rs2, l2r, a2) SUMR(3, rs3, l3r, a3)

    if (col == 0) {
      alpha_s[wave * 16 + grp * 4 + 0] = a0;
      alpha_s[wave * 16 + grp * 4 + 1] = a1;
      alpha_s[wave * 16 + grp * 4 + 2] = a2;
      alpha_s[wave * 16 + grp * 4 + 3] = a3;
    }
    __syncthreads();   // p_s/alpha_s ready; kv_s(ch) free

    if (ch + 1 < nch) STAGE(t0 + 32)   // overlaps PV below

    // ---- rescale (alpha broadcast from LDS) ----
#define RESC(i) { f32x4 av = (f32x4){alpha_s[(i)*16 + grp*4 + 0], alpha_s[(i)*16 + grp*4 + 1], \
                                     alpha_s[(i)*16 + grp*4 + 2], alpha_s[(i)*16 + grp*4 + 3]}; \
    o##i##0 *= av; o##i##1 *= av; o##i##2 *= av; o##i##3 *= av; }
    RESC(0) RESC(1) RESC(2) RESC(3)

    // ---- PV: d-partition, vf straight from global kvT ----
    s16x8 pf0 = *(const s16x8*)&p_s[(0 * 16 + col) * 40 + grp * 8];
    s16x8 pf1 = *(const s16x8*)&p_s[(1 * 16 + col) * 40 + grp * 8];
    s16x8 pf2 = *(const s16x8*)&p_s[(2 * 16 + col) * 40 + grp * 8];
    s16x8 pf3 = *(const s16x8*)&p_s[(3 * 16 + col) * 40 + grp * 8];
#define PVJ(j) { \
      s16x8 vf = *(const s16x8*)(kvT + (size_t)(wave * 64 + (j) * 16 + col) * S_LEN + t0 + grp * 8); \
      o0##j = MFMA(pf0, vf, o0##j); o1##j = MFMA(pf1, vf, o1##j); \
      o2##j = MFMA(pf2, vf, o2##j); o3##j = MFMA(pf3, vf, o3##j); }
    PVJ(0) PVJ(1) PVJ(2) PVJ(3)
  }

  // ---- inv broadcast ----
  const float sk = sink[h];
  {
    float i0 = 1.f / (l0r + __expf(sk - m0r));
    float i1 = 1.f / (l1r + __expf(sk - m1r));
    float i2 = 1.f / (l2r + __expf(sk - m2r));
    float i3 = 1.f / (l3r + __expf(sk - m3r));
    if (col == 0) {
      inv_s[wave * 16 + grp * 4 + 0] = i0;
      inv_s[wave * 16 + grp * 4 + 1] = i1;
      inv_s[wave * 16 + grp * 4 + 2] = i2;
      inv_s[wave * 16 + grp * 4 + 3] = i3;
    }
  }
  __syncthreads();

  // ---- epilogue: normalize, conj-RoPE (wave 3 owns dims 192..255), store ----
#define EPIJ(i, j, onam, ivv) { \
    float v0 = onam[0] * ivv[0]; float v1 = onam[1] * ivv[1]; \
    float v2 = onam[2] * ivv[2]; float v3 = onam[3] * ivv[3]; \
    if (wave == 3) { \
      int jr = ((j) * 16 + col) >> 1; \
      float f0 = freqs[(size_t)(q0 + (i) * 16 + grp * 4 + 0) * 32 + jr]; \
      float f1 = freqs[(size_t)(q0 + (i) * 16 + grp * 4 + 1) * 32 + jr]; \
      float f2 = freqs[(size_t)(q0 + (i) * 16 + grp * 4 + 2) * 32 + jr]; \
      float f3 = freqs[(size_t)(q0 + (i) * 16 + grp * 4 + 3) * 32 + jr]; \
      float p0 = __shfl_xor(v0, 1), p1 = __shfl_xor(v1, 1); \
      float p2 = __shfl_xor(v2, 1), p3 = __shfl_xor(v3, 1); \
      v0 = (col & 1) ? (v0 * cosf(f0) - p0 * sinf(f0)) : (v0 * cosf(f0) + p0 * sinf(f0)); \
      v1 = (col & 1) ? (v1 * cosf(f1) - p1 * sinf(f1)) : (v1 * cosf(f1) + p1 * sinf(f1)); \
      v2 = (col & 1) ? (v2 * cosf(f2) - p2 * sinf(f2)) : (v2 * cosf(f2) + p2 * sinf(f2)); \
      v3 = (col & 1) ? (v3 * cosf(f3) - p3 * sinf(f3)) : (v3 * cosf(f3) + p3 * sinf(f3)); \
    } \
    size_t obase = (size_t)(q0 + (i) * 16 + grp * 4) * (NH * HD) + (size_t)h * HD + \
                   wave * 64 + (j) * 16 + col; \
    ob[obase] = f2bf(v0); ob[obase + (NH * HD)] = f2bf(v1); \
    ob[obase + 2 * (NH * HD)] = f2bf(v2); ob[obase + 3 * (NH * HD)] = f2bf(v3); }
#define EPII(i) { \
    f32x4 ivv = (f32x4){inv_s[(i)*16 + grp*4 + 0], inv_s[(i)*16 + grp*4 + 1], \
                        inv_s[(i)*16 + grp*4 + 2], inv_s[(i)*16 + grp*4 + 3]}; \
    EPIJ(i, 0, o##i##0, ivv) EPIJ(i, 1, o##i##1, ivv) \
    EPIJ(i, 2, o##i##2, ivv) EPIJ(i, 3, o##i##3, ivv) }
  EPII(0) EPII(1) EPII(2) EPII(3)
}

extern "C" void kernel_launch(void* const* d_in, const int* in_sizes, int n_in,
                              void* d_out, int out_size, void* d_ws, size_t ws_size,
                              hipStream_t stream) {
  const float* x         = (const float*)d_in[0];
  const float* freqs     = (const float*)d_in[1];
  const float* wq_a      = (const float*)d_in[2];
  const float* q_norm_w  = (const float*)d_in[3];
  const float* wq_b      = (const float*)d_in[4];
  const float* wkv       = (const float*)d_in[5];
  const float* kv_norm_w = (const float*)d_in[6];
  const float* wo_a_w    = (const float*)d_in[7];
  const float* wo_b      = (const float*)d_in[8];
  const float* sink      = (const float*)d_in[9];
  float* out = (float*)d_out;

  // Workspace (byte offsets, 55 MB total):
  //  [0,4M)    qa_bf
  //  [4M,20M)  q_bf (G2 out -> attn). After attn: orb_bf [4M,12M), wob_bf [12M,20M)
  //  [20M,36M) o_bf (attn out); x_bf [20M,28M) dead before attn writes.
  //  [36M,40M) wqa_bf  [40M,48M) wqb_bf  [48M,49M) wkv_bf
  //  [49M,53M) woa_bf  [53M,54M) kv_bf  [54M,55M) kvT_bf
  char* ws = (char*)d_ws;
  const size_t MB = 1024 * 1024;
  unsigned short* qa_bf   = (unsigned short*)(ws + 0 * MB);
  unsigned short* q_bf    = (unsigned short*)(ws + 4 * MB);
  unsigned short* orb_bf  = (unsigned short*)(ws + 4 * MB);
  unsigned short* wob_bf  = (unsigned short*)(ws + 12 * MB);
  unsigned short* o_bf    = (unsigned short*)(ws + 20 * MB);
  unsigned short* x_bf    = (unsigned short*)(ws + 20 * MB);
  unsigned short* wqa_bf  = (unsigned short*)(ws + 36 * MB);
  unsigned short* wqb_bf  = (unsigned short*)(ws + 40 * MB);
  unsigned short* wkv_bf  = (unsigned short*)(ws + 48 * MB);
  unsigned short* woa_bf  = (unsigned short*)(ws + 49 * MB);
  unsigned short* kv_bf   = (unsigned short*)(ws + 53 * MB);
  unsigned short* kvT_bf  = (unsigned short*)(ws + 54 * MB);

  dim3 blk(256);

  // 0) fp32 -> bf16 conversions (wo_b deferred until after attention)
  f32_to_bf16<<<dim3(4096), blk, 0, stream>>>(x,      x_bf,   4 * 1024 * 1024 / 4);
  f32_to_bf16<<<dim3(2048), blk, 0, stream>>>(wq_a,   wqa_bf, 2 * 1024 * 1024 / 4);
  f32_to_bf16<<<dim3(4096), blk, 0, stream>>>(wq_b,   wqb_bf, 4 * 1024 * 1024 / 4);
  f32_to_bf16<<<dim3(512),  blk, 0, stream>>>(wkv,    wkv_bf, 512 * 1024 / 4);
  f32_to_bf16<<<dim3(2048), blk, 0, stream>>>(wo_a_w, woa_bf, 2 * 1024 * 1024 / 4);

  // 1) qa = x @ wq_a^T  (2048x1024, K=2048) -> bf16
  gemm_bf16<<<dim3(QL / 128, S_LEN / 128, 1), blk, 0, stream>>>(
      x_bf, wqa_bf, qa_bf, HID, HID, HID, QL, 0, 0, 0, 1);
  // 2) RMS in-place
  rmsnorm_bf_ip<<<dim3(S_LEN), blk, 0, stream>>>(qa_bf, q_norm_w, QL);
  // 3) q = qa @ wq_b^T  (2048x4096, K=1024) -> bf16
  gemm_bf16<<<dim3(NH * HD / 128, S_LEN / 128, 1), blk, 0, stream>>>(
      qa_bf, wqb_bf, q_bf, QL, QL, QL, NH * HD, 0, 0, 0, 1);
  // 4) per-(s,h) RMS + RoPE in-place
  qnorm_rope_ip<<<dim3(S_LEN * NH), blk, 0, stream>>>(q_bf, freqs);
  // 5) kv = x @ wkv^T   (2048x256, K=2048) -> bf16
  gemm_bf16<<<dim3(HD / 128, S_LEN / 128, 1), blk, 0, stream>>>(
      x_bf, wkv_bf, kv_bf, HID, HID, HID, HD, 0, 0, 0, 1);
  // 6) RMS + RoPE in-place, also emit kvT
  kvnorm_rope_ip<<<dim3(S_LEN), blk, 0, stream>>>(kv_bf, kv_norm_w, freqs, kvT_bf);
  // 7) flash attention -> o_bf
  attn_mfma<<<dim3(S_LEN / 64, NH), blk, 0, stream>>>(q_bf, kv_bf, kvT_bf, sink, freqs, o_bf);
  // 7b) convert wo_b into [12M,20M) — q_bf dead after attention
  f32_to_bf16<<<dim3(4096), blk, 0, stream>>>(wo_b, wob_bf, 4 * 1024 * 1024 / 4);
  // 8) grouped projection via z-grid
  gemm_bf16<<<dim3(OR_ / 128, S_LEN / 128, NG), blk, 0, stream>>>(
      o_bf, woa_bf, orb_bf, HPG * HD, NH * HD, HPG * HD, NG * OR_,
      (long)(HPG * HD), (long)OR_ * (HPG * HD), (long)OR_, 1);
  // 9) out = orb @ wo_b^T (2048x2048, K=2048) -> fp32
  gemm_bf16<<<dim3(HID / 128, S_LEN / 128, 1), blk, 0, stream>>>(
      orb_bf, wob_bf, out, NG * OR_, NG * OR_, NG * OR_, HID, 0, 0, 0, 0);
}

// Round 9
// 519.025 us; speedup vs baseline: 1.2896x; 1.2896x over previous
//
#include <hip/hip_runtime.h>
#include <hip/hip_bf16.h>

// Problem constants (B=1)
#define S_LEN 2048
#define HID 2048
#define NH 16
#define HD 256
#define NROT 64
#define NOPE 192
#define QL 1024
#define OR_ 512
#define NG 4
#define HPG 4
#define EPS 1e-6f
#define SCALE 0.0625f   // 256^-0.5

typedef __bf16 bf16x8 __attribute__((ext_vector_type(8)));
typedef short s16x8 __attribute__((ext_vector_type(8)));
typedef float f32x4 __attribute__((ext_vector_type(4)));

#define MFMA(a, b, c) __builtin_amdgcn_mfma_f32_16x16x32_bf16( \
    __builtin_bit_cast(bf16x8, a), __builtin_bit_cast(bf16x8, b), c, 0, 0, 0)

__device__ __forceinline__ unsigned short f2bf(float x) {
  unsigned int u = __builtin_bit_cast(unsigned int, x);
  u += 0x7FFFu + ((u >> 16) & 1u);   // RNE
  return (unsigned short)(u >> 16);
}
__device__ __forceinline__ float bf2f(unsigned short b) {
  unsigned int u = ((unsigned int)b) << 16;
  return __builtin_bit_cast(float, u);
}

// ---------------- fp32 -> bf16 convert (vectorized) ----------------
__global__ __launch_bounds__(256) void f32_to_bf16(const float* __restrict__ in,
                                                   unsigned short* __restrict__ out, int n4) {
  int i = blockIdx.x * 256 + threadIdx.x;
  if (i < n4) {
    float4 v = ((const float4*)in)[i];
    ushort4 o;
    o.x = f2bf(v.x); o.y = f2bf(v.y); o.z = f2bf(v.z); o.w = f2bf(v.w);
    ((ushort4*)out)[i] = o;
  }
}

// ---------------- bf16 MFMA GEMM: C[M,N] = A[M,K] @ B[N,K]^T ----------------
__global__ __launch_bounds__(256, 2) void gemm_bf16(
    const unsigned short* __restrict__ A, const unsigned short* __restrict__ B,
    void* __restrict__ Cv, int K, int lda, int ldb, int ldc,
    long aoffz, long boffz, long coffz, int store_bf) {
  __shared__ __align__(16) unsigned short As[128 * 40];
  __shared__ __align__(16) unsigned short Bs[128 * 40];
  A += (size_t)blockIdx.z * aoffz;
  B += (size_t)blockIdx.z * boffz;
  const int tid = threadIdx.x;
  const int wave = tid >> 6, lane = tid & 63;
  const int col = lane & 15, grp = lane >> 4;
  const int wm = wave >> 1, wn = wave & 1;
  const int m0 = blockIdx.y * 128, n0 = blockIdx.x * 128;

  f32x4 acc[4][4];
#pragma unroll
  for (int i = 0; i < 4; ++i)
#pragma unroll
    for (int j = 0; j < 4; ++j) acc[i][j] = (f32x4){0.f, 0.f, 0.f, 0.f};

  for (int k0 = 0; k0 < K; k0 += 32) {
#pragma unroll
    for (int u = 0; u < 2; ++u) {
      int lin = u * 256 + tid;
      int r = lin >> 2, c8 = (lin & 3) * 8;
      *(s16x8*)&As[r * 40 + c8] = *(const s16x8*)(A + (size_t)(m0 + r) * lda + k0 + c8);
      *(s16x8*)&Bs[r * 40 + c8] = *(const s16x8*)(B + (size_t)(n0 + r) * ldb + k0 + c8);
    }
    __syncthreads();
    s16x8 a[4], b[4];
#pragma unroll
    for (int i = 0; i < 4; ++i)
      a[i] = *(const s16x8*)&As[(wm * 64 + i * 16 + col) * 40 + grp * 8];
#pragma unroll
    for (int j = 0; j < 4; ++j)
      b[j] = *(const s16x8*)&Bs[(wn * 64 + j * 16 + col) * 40 + grp * 8];
#pragma unroll
    for (int i = 0; i < 4; ++i)
#pragma unroll
      for (int j = 0; j < 4; ++j)
        acc[i][j] = MFMA(a[i], b[j], acc[i][j]);
    __syncthreads();
  }

  if (store_bf) {
    unsigned short* C = (unsigned short*)Cv + (size_t)blockIdx.z * coffz;
#pragma unroll
    for (int i = 0; i < 4; ++i)
#pragma unroll
      for (int j = 0; j < 4; ++j)
#pragma unroll
        for (int r = 0; r < 4; ++r)
          C[(size_t)(m0 + wm * 64 + i * 16 + grp * 4 + r) * ldc +
            n0 + wn * 64 + j * 16 + col] = f2bf(acc[i][j][r]);
  } else {
    float* C = (float*)Cv + (size_t)blockIdx.z * coffz;
#pragma unroll
    for (int i = 0; i < 4; ++i)
#pragma unroll
      for (int j = 0; j < 4; ++j)
#pragma unroll
        for (int r = 0; r < 4; ++r)
          C[(size_t)(m0 + wm * 64 + i * 16 + grp * 4 + r) * ldc +
            n0 + wn * 64 + j * 16 + col] = acc[i][j][r];
  }
}

// ---------------- RMSNorm (weighted) in-place on bf16 rows of length L ----------------
__global__ __launch_bounds__(256) void rmsnorm_bf_ip(unsigned short* __restrict__ x,
                                                     const float* __restrict__ w, int L) {
  int row = blockIdx.x;
  unsigned short* p = x + (size_t)row * L;
  __shared__ float red[256];
  float s = 0.f;
  for (int i = threadIdx.x; i < L; i += 256) { float v = bf2f(p[i]); s += v * v; }
  red[threadIdx.x] = s;
  __syncthreads();
  for (int off = 128; off > 0; off >>= 1) {
    if (threadIdx.x < off) red[threadIdx.x] += red[threadIdx.x + off];
    __syncthreads();
  }
  float r = rsqrtf(red[0] / (float)L + EPS);
  for (int i = threadIdx.x; i < L; i += 256) p[i] = f2bf(bf2f(p[i]) * r * w[i]);
}

// ---------------- Q per-head RMS (no weight) + RoPE, in-place bf16 ----------------
__global__ __launch_bounds__(256) void qnorm_rope_ip(unsigned short* __restrict__ q,
                                                     const float* __restrict__ freqs) {
  int row = blockIdx.x;       // s*NH + h
  int s = row / NH;
  unsigned short* p = q + (size_t)row * HD;
  int d = threadIdx.x;
  float v = bf2f(p[d]);
  __shared__ float red[256];
  __shared__ float sm[256];
  red[d] = v * v;
  __syncthreads();
  for (int off = 128; off > 0; off >>= 1) {
    if (d < off) red[d] += red[d + off];
    __syncthreads();
  }
  float r = rsqrtf(red[0] / 256.0f + EPS);
  float nv = v * r;
  sm[d] = nv;
  __syncthreads();
  float outv = nv;
  if (d >= NOPE) {
    int j = (d - NOPE) >> 1;
    float f = freqs[(size_t)s * (NROT / 2) + j];
    float c = cosf(f), si = sinf(f);
    float x1 = sm[NOPE + 2 * j], x2 = sm[NOPE + 2 * j + 1];
    outv = ((d & 1) == 0) ? (x1 * c - x2 * si) : (x1 * si + x2 * c);
  }
  p[d] = f2bf(outv);
}

// ---------------- KV RMS (weighted) + RoPE, in-place bf16 + kvT global ----------------
__global__ __launch_bounds__(256) void kvnorm_rope_ip(unsigned short* __restrict__ kv,
                                                      const float* __restrict__ w,
                                                      const float* __restrict__ freqs,
                                                      unsigned short* __restrict__ kvT) {
  int s = blockIdx.x;
  unsigned short* p = kv + (size_t)s * HD;
  int d = threadIdx.x;
  float v = bf2f(p[d]);
  __shared__ float red[256];
  __shared__ float sm[256];
  red[d] = v * v;
  __syncthreads();
  for (int off = 128; off > 0; off >>= 1) {
    if (d < off) red[d] += red[d + off];
    __syncthreads();
  }
  float r = rsqrtf(red[0] / 256.0f + EPS);
  float nv = v * r * w[d];
  sm[d] = nv;
  __syncthreads();
  float outv = nv;
  if (d >= NOPE) {
    int j = (d - NOPE) >> 1;
    float f = freqs[(size_t)s * (NROT / 2) + j];
    float c = cosf(f), si = sinf(f);
    float x1 = sm[NOPE + 2 * j], x2 = sm[NOPE + 2 * j + 1];
    outv = ((d & 1) == 0) ? (x1 * c - x2 * si) : (x1 * si + x2 * c);
  }
  unsigned short ov = f2bf(outv);
  p[d] = ov;
  kvT[(size_t)d * S_LEN + s] = ov;   // transposed copy for PV B-frags
}

// ---------------- MFMA flash attention v4 ----------------
// R8 lesson: inline global vf loads in PV = latency-bound. v4 prefetches ALL
// global traffic (this chunk's 4 vf B-frags + next chunk's 4 kv staging rows)
// into named registers at the TOP of the chunk, hiding L2 latency behind
// QK MFMA + softmax. ds_writes of staged regs land after the p_s barrier.
// No addressable arrays (R7 lesson). LDS 22.5 KB.
__global__ __launch_bounds__(256, 2) void attn_mfma(
    const unsigned short* __restrict__ qbf,   // (S, NH*HD) bf16
    const unsigned short* __restrict__ kvbf,  // (S, HD) bf16
    const unsigned short* __restrict__ kvT,   // (HD, S) bf16
    const float* __restrict__ sink,
    const float* __restrict__ freqs,
    unsigned short* __restrict__ ob) {        // (S, NH*HD) bf16
  __shared__ __align__(16) unsigned short kv_s[32 * 264];  // [t][d]
  __shared__ __align__(16) unsigned short p_s[64 * 40];    // [row][t]
  __shared__ float alpha_s[64];
  __shared__ float inv_s[64];

  const int tid = threadIdx.x;
  const int wave = tid >> 6, lane = tid & 63;
  const int col = lane & 15, grp = lane >> 4;
  const int q0 = (gridDim.x - 1 - blockIdx.x) * 64;   // big tiles first (LPT)
  const int h = blockIdx.y;
  const int qrow = q0 + wave * 16;

  // Q fragments: 8 named s16x8 regs (32 VGPRs)
  const unsigned short* qbase =
      qbf + (size_t)(qrow + col) * (NH * HD) + (size_t)h * HD + grp * 8;
#define QDECL(ko, nam) s16x8 nam = *(const s16x8*)(qbase + (ko) * 32);
  QDECL(0, qf0) QDECL(1, qf1) QDECL(2, qf2) QDECL(3, qf3)
  QDECL(4, qf4) QDECL(5, qf5) QDECL(6, qf6) QDECL(7, qf7)

  const f32x4 z4 = (f32x4){0.f, 0.f, 0.f, 0.f};
  float m0r = -1e30f, m1r = -1e30f, m2r = -1e30f, m3r = -1e30f;
  float l0r = 0.f, l1r = 0.f, l2r = 0.f, l3r = 0.f;

#define FOR16(M) M(0,0,o00) M(0,1,o01) M(0,2,o02) M(0,3,o03) \
                 M(1,0,o10) M(1,1,o11) M(1,2,o12) M(1,3,o13) \
                 M(2,0,o20) M(2,1,o21) M(2,2,o22) M(2,3,o23) \
                 M(3,0,o30) M(3,1,o31) M(3,2,o32) M(3,3,o33)
#define DECLO(i, j, onam) f32x4 onam = z4;
  FOR16(DECLO)

  // Staging lane geometry: thread owns rows {tS, tS+8, tS+16, tS+24}, cols [ddS, ddS+8)
  const int tS = tid >> 5, ddS = (tid & 31) * 8;

  // Initial stage of chunk 0 (direct load -> LDS write; fenced by first barrier)
  {
    const unsigned short* sb = kvbf + (size_t)tS * HD + ddS;
    *(s16x8*)&kv_s[tS * 264 + ddS]        = *(const s16x8*)(sb);
    *(s16x8*)&kv_s[(tS + 8) * 264 + ddS]  = *(const s16x8*)(sb + 8 * HD);
    *(s16x8*)&kv_s[(tS + 16) * 264 + ddS] = *(const s16x8*)(sb + 16 * HD);
    *(s16x8*)&kv_s[(tS + 24) * 264 + ddS] = *(const s16x8*)(sb + 24 * HD);
  }

  const int nch = q0 / 32 + 2;
  for (int ch = 0; ch < nch; ++ch) {
    const int t0 = ch * 32;
    __syncthreads();   // kv_s(ch) ready; p_s/alpha_s(ch-1) fully consumed

    // ---- PREFETCH (fire-and-forget; consumed after ~400 cyc of QK+softmax) ----
    const bool havest = (ch + 1 < nch);
    s16x8 st0 = {}, st1 = {}, st2 = {}, st3 = {};
    if (havest) {
      const unsigned short* sb = kvbf + (size_t)(t0 + 32 + tS) * HD + ddS;
      st0 = *(const s16x8*)(sb);
      st1 = *(const s16x8*)(sb + 8 * HD);
      st2 = *(const s16x8*)(sb + 16 * HD);
      st3 = *(const s16x8*)(sb + 24 * HD);
    }
    const unsigned short* vb = kvT + (size_t)(wave * 64 + col) * S_LEN + t0 + grp * 8;
    s16x8 vf0 = *(const s16x8*)(vb);
    s16x8 vf1 = *(const s16x8*)(vb + 16 * S_LEN);
    s16x8 vf2 = *(const s16x8*)(vb + 32 * S_LEN);
    s16x8 vf3 = *(const s16x8*)(vb + 48 * S_LEN);

    // ---- QK^T ----
    f32x4 s0 = z4, s1 = z4;
#define QKS(ko, qf) { \
      s16x8 b0 = *(const s16x8*)&kv_s[col * 264 + (ko) * 32 + grp * 8]; \
      s16x8 b1 = *(const s16x8*)&kv_s[(16 + col) * 264 + (ko) * 32 + grp * 8]; \
      s0 = MFMA(qf, b0, s0); s1 = MFMA(qf, b1, s1); }
    QKS(0, qf0) QKS(1, qf1) QKS(2, qf2) QKS(3, qf3)
    QKS(4, qf4) QKS(5, qf5) QKS(6, qf6) QKS(7, qf7)

    // ---- scale + causal mask ----
#define MASKR(r) { int sg = qrow + grp * 4 + (r); \
    s0[r] = (t0 + col <= sg) ? s0[r] * SCALE : -1e30f; \
    s1[r] = (t0 + 16 + col <= sg) ? s1[r] * SCALE : -1e30f; }
    MASKR(0) MASKR(1) MASKR(2) MASKR(3)

    // ---- online softmax ----
    float a0, a1, a2, a3;
#define MAXR(r, mr, ar) { float v = fmaxf(s0[r], s1[r]); \
    v = fmaxf(v, __shfl_xor(v, 1)); v = fmaxf(v, __shfl_xor(v, 2)); \
    v = fmaxf(v, __shfl_xor(v, 4)); v = fmaxf(v, __shfl_xor(v, 8)); \
    float mn = fmaxf(mr, v); ar = __expf(mr - mn); mr = mn; }
    MAXR(0, m0r, a0) MAXR(1, m1r, a1) MAXR(2, m2r, a2) MAXR(3, m3r, a3)

    float rs0, rs1, rs2, rs3;
#define PROW(r, mr, rsr) { float p0 = __expf(s0[r] - mr); float p1 = __expf(s1[r] - mr); \
    rsr = p0 + p1; \
    p_s[(wave * 16 + grp * 4 + (r)) * 40 + col] = f2bf(p0); \
    p_s[(wave * 16 + grp * 4 + (r)) * 40 + 16 + col] = f2bf(p1); }
    PROW(0, m0r, rs0) PROW(1, m1r, rs1) PROW(2, m2r, rs2) PROW(3, m3r, rs3)

#define SUMR(r, rsr, lr, ar) { float v = rsr; \
    v += __shfl_xor(v, 1); v += __shfl_xor(v, 2); \
    v += __shfl_xor(v, 4); v += __shfl_xor(v, 8); \
    lr = lr * ar + v; }
    SUMR(0, rs0, l0r, a0) SUMR(1, rs1, l1r, a1) SUMR(2, rs2, l2r, a2) SUMR(3, rs3, l3r, a3)

    if (col == 0) {
      alpha_s[wave * 16 + grp * 4 + 0] = a0;
      alpha_s[wave * 16 + grp * 4 + 1] = a1;
      alpha_s[wave * 16 + grp * 4 + 2] = a2;
      alpha_s[wave * 16 + grp * 4 + 3] = a3;
    }
    __syncthreads();   // p_s/alpha_s ready; all kv_s(ch) reads complete

    // ---- commit prefetched next chunk into kv_s (regs already resident) ----
    if (havest) {
      *(s16x8*)&kv_s[tS * 264 + ddS]        = st0;
      *(s16x8*)&kv_s[(tS + 8) * 264 + ddS]  = st1;
      *(s16x8*)&kv_s[(tS + 16) * 264 + ddS] = st2;
      *(s16x8*)&kv_s[(tS + 24) * 264 + ddS] = st3;
    }

    // ---- rescale (alpha broadcast from LDS) ----
#define RESC(i) { f32x4 av = (f32x4){alpha_s[(i)*16 + grp*4 + 0], alpha_s[(i)*16 + grp*4 + 1], \
                                     alpha_s[(i)*16 + grp*4 + 2], alpha_s[(i)*16 + grp*4 + 3]}; \
    o##i##0 *= av; o##i##1 *= av; o##i##2 *= av; o##i##3 *= av; }
    RESC(0) RESC(1) RESC(2) RESC(3)

    // ---- PV: d-partition, vf from prefetched regs ----
    s16x8 pf0 = *(const s16x8*)&p_s[(0 * 16 + col) * 40 + grp * 8];
    s16x8 pf1 = *(const s16x8*)&p_s[(1 * 16 + col) * 40 + grp * 8];
    s16x8 pf2 = *(const s16x8*)&p_s[(2 * 16 + col) * 40 + grp * 8];
    s16x8 pf3 = *(const s16x8*)&p_s[(3 * 16 + col) * 40 + grp * 8];
#define PVJ(j, vf) { \
      o0##j = MFMA(pf0, vf, o0##j); o1##j = MFMA(pf1, vf, o1##j); \
      o2##j = MFMA(pf2, vf, o2##j); o3##j = MFMA(pf3, vf, o3##j); }
    PVJ(0, vf0) PVJ(1, vf1) PVJ(2, vf2) PVJ(3, vf3)
  }

  // ---- inv broadcast ----
  const float sk = sink[h];
  {
    float i0 = 1.f / (l0r + __expf(sk - m0r));
    float i1 = 1.f / (l1r + __expf(sk - m1r));
    float i2 = 1.f / (l2r + __expf(sk - m2r));
    float i3 = 1.f / (l3r + __expf(sk - m3r));
    if (col == 0) {
      inv_s[wave * 16 + grp * 4 + 0] = i0;
      inv_s[wave * 16 + grp * 4 + 1] = i1;
      inv_s[wave * 16 + grp * 4 + 2] = i2;
      inv_s[wave * 16 + grp * 4 + 3] = i3;
    }
  }
  __syncthreads();

  // ---- epilogue: normalize, conj-RoPE (wave 3 owns dims 192..255), store ----
#define EPIJ(i, j, onam, ivv) { \
    float v0 = onam[0] * ivv[0]; float v1 = onam[1] * ivv[1]; \
    float v2 = onam[2] * ivv[2]; float v3 = onam[3] * ivv[3]; \
    if (wave == 3) { \
      int jr = ((j) * 16 + col) >> 1; \
      float f0 = freqs[(size_t)(q0 + (i) * 16 + grp * 4 + 0) * 32 + jr]; \
      float f1 = freqs[(size_t)(q0 + (i) * 16 + grp * 4 + 1) * 32 + jr]; \
      float f2 = freqs[(size_t)(q0 + (i) * 16 + grp * 4 + 2) * 32 + jr]; \
      float f3 = freqs[(size_t)(q0 + (i) * 16 + grp * 4 + 3) * 32 + jr]; \
      float p0 = __shfl_xor(v0, 1), p1 = __shfl_xor(v1, 1); \
      float p2 = __shfl_xor(v2, 1), p3 = __shfl_xor(v3, 1); \
      v0 = (col & 1) ? (v0 * cosf(f0) - p0 * sinf(f0)) : (v0 * cosf(f0) + p0 * sinf(f0)); \
      v1 = (col & 1) ? (v1 * cosf(f1) - p1 * sinf(f1)) : (v1 * cosf(f1) + p1 * sinf(f1)); \
      v2 = (col & 1) ? (v2 * cosf(f2) - p2 * sinf(f2)) : (v2 * cosf(f2) + p2 * sinf(f2)); \
      v3 = (col & 1) ? (v3 * cosf(f3) - p3 * sinf(f3)) : (v3 * cosf(f3) + p3 * sinf(f3)); \
    } \
    size_t obase = (size_t)(q0 + (i) * 16 + grp * 4) * (NH * HD) + (size_t)h * HD + \
                   wave * 64 + (j) * 16 + col; \
    ob[obase] = f2bf(v0); ob[obase + (NH * HD)] = f2bf(v1); \
    ob[obase + 2 * (NH * HD)] = f2bf(v2); ob[obase + 3 * (NH * HD)] = f2bf(v3); }
#define EPII(i) { \
    f32x4 ivv = (f32x4){inv_s[(i)*16 + grp*4 + 0], inv_s[(i)*16 + grp*4 + 1], \
                        inv_s[(i)*16 + grp*4 + 2], inv_s[(i)*16 + grp*4 + 3]}; \
    EPIJ(i, 0, o##i##0, ivv) EPIJ(i, 1, o##i##1, ivv) \
    EPIJ(i, 2, o##i##2, ivv) EPIJ(i, 3, o##i##3, ivv) }
  EPII(0) EPII(1) EPII(2) EPII(3)
}

extern "C" void kernel_launch(void* const* d_in, const int* in_sizes, int n_in,
                              void* d_out, int out_size, void* d_ws, size_t ws_size,
                              hipStream_t stream) {
  const float* x         = (const float*)d_in[0];
  const float* freqs     = (const float*)d_in[1];
  const float* wq_a      = (const float*)d_in[2];
  const float* q_norm_w  = (const float*)d_in[3];
  const float* wq_b      = (const float*)d_in[4];
  const float* wkv       = (const float*)d_in[5];
  const float* kv_norm_w = (const float*)d_in[6];
  const float* wo_a_w    = (const float*)d_in[7];
  const float* wo_b      = (const float*)d_in[8];
  const float* sink      = (const float*)d_in[9];
  float* out = (float*)d_out;

  // Workspace (byte offsets, 55 MB total):
  //  [0,4M)    qa_bf
  //  [4M,20M)  q_bf (G2 out -> attn). After attn: orb_bf [4M,12M), wob_bf [12M,20M)
  //  [20M,36M) o_bf (attn out); x_bf [20M,28M) dead before attn writes.
  //  [36M,40M) wqa_bf  [40M,48M) wqb_bf  [48M,49M) wkv_bf
  //  [49M,53M) woa_bf  [53M,54M) kv_bf  [54M,55M) kvT_bf
  char* ws = (char*)d_ws;
  const size_t MB = 1024 * 1024;
  unsigned short* qa_bf   = (unsigned short*)(ws + 0 * MB);
  unsigned short* q_bf    = (unsigned short*)(ws + 4 * MB);
  unsigned short* orb_bf  = (unsigned short*)(ws + 4 * MB);
  unsigned short* wob_bf  = (unsigned short*)(ws + 12 * MB);
  unsigned short* o_bf    = (unsigned short*)(ws + 20 * MB);
  unsigned short* x_bf    = (unsigned short*)(ws + 20 * MB);
  unsigned short* wqa_bf  = (unsigned short*)(ws + 36 * MB);
  unsigned short* wqb_bf  = (unsigned short*)(ws + 40 * MB);
  unsigned short* wkv_bf  = (unsigned short*)(ws + 48 * MB);
  unsigned short* woa_bf  = (unsigned short*)(ws + 49 * MB);
  unsigned short* kv_bf   = (unsigned short*)(ws + 53 * MB);
  unsigned short* kvT_bf  = (unsigned short*)(ws + 54 * MB);

  dim3 blk(256);

  // 0) fp32 -> bf16 conversions (wo_b deferred until after attention)
  f32_to_bf16<<<dim3(4096), blk, 0, stream>>>(x,      x_bf,   4 * 1024 * 1024 / 4);
  f32_to_bf16<<<dim3(2048), blk, 0, stream>>>(wq_a,   wqa_bf, 2 * 1024 * 1024 / 4);
  f32_to_bf16<<<dim3(4096), blk, 0, stream>>>(wq_b,   wqb_bf, 4 * 1024 * 1024 / 4);
  f32_to_bf16<<<dim3(512),  blk, 0, stream>>>(wkv,    wkv_bf, 512 * 1024 / 4);
  f32_to_bf16<<<dim3(2048), blk, 0, stream>>>(wo_a_w, woa_bf, 2 * 1024 * 1024 / 4);

  // 1) qa = x @ wq_a^T  (2048x1024, K=2048) -> bf16
  gemm_bf16<<<dim3(QL / 128, S_LEN / 128, 1), blk, 0, stream>>>(
      x_bf, wqa_bf, qa_bf, HID, HID, HID, QL, 0, 0, 0, 1);
  // 2) RMS in-place
  rmsnorm_bf_ip<<<dim3(S_LEN), blk, 0, stream>>>(qa_bf, q_norm_w, QL);
  // 3) q = qa @ wq_b^T  (2048x4096, K=1024) -> bf16
  gemm_bf16<<<dim3(NH * HD / 128, S_LEN / 128, 1), blk, 0, stream>>>(
      qa_bf, wqb_bf, q_bf, QL, QL, QL, NH * HD, 0, 0, 0, 1);
  // 4) per-(s,h) RMS + RoPE in-place
  qnorm_rope_ip<<<dim3(S_LEN * NH), blk, 0, stream>>>(q_bf, freqs);
  // 5) kv = x @ wkv^T   (2048x256, K=2048) -> bf16
  gemm_bf16<<<dim3(HD / 128, S_LEN / 128, 1), blk, 0, stream>>>(
      x_bf, wkv_bf, kv_bf, HID, HID, HID, HD, 0, 0, 0, 1);
  // 6) RMS + RoPE in-place, also emit kvT
  kvnorm_rope_ip<<<dim3(S_LEN), blk, 0, stream>>>(kv_bf, kv_norm_w, freqs, kvT_bf);
  // 7) flash attention -> o_bf
  attn_mfma<<<dim3(S_LEN / 64, NH), blk, 0, stream>>>(q_bf, kv_bf, kvT_bf, sink, freqs, o_bf);
  // 7b) convert wo_b into [12M,20M) — q_bf dead after attention
  f32_to_bf16<<<dim3(4096), blk, 0, stream>>>(wo_b, wob_bf, 4 * 1024 * 1024 / 4);
  // 8) grouped projection via z-grid
  gemm_bf16<<<dim3(OR_ / 128, S_LEN / 128, NG), blk, 0, stream>>>(
      o_bf, woa_bf, orb_bf, HPG * HD, NH * HD, HPG * HD, NG * OR_,
      (long)(HPG * HD), (long)OR_ * (HPG * HD), (long)OR_, 1);
  // 9) out = orb @ wo_b^T (2048x2048, K=2048) -> fp32
  gemm_bf16<<<dim3(HID / 128, S_LEN / 128, 1), blk, 0, stream>>>(
      orb_bf, wob_bf, out, NG * OR_, NG * OR_, NG * OR_, HID, 0, 0, 0, 0);
}

// Round 10
// 474.804 us; speedup vs baseline: 1.4097x; 1.0931x over previous
//
#include <hip/hip_runtime.h>
#include <hip/hip_bf16.h>

// Problem constants (B=1)
#define S_LEN 2048
#define HID 2048
#define NH 16
#define HD 256
#define NROT 64
#define NOPE 192
#define QL 1024
#define OR_ 512
#define NG 4
#define HPG 4
#define EPS 1e-6f
#define SCALE 0.0625f   // 256^-0.5

typedef __bf16 bf16x8 __attribute__((ext_vector_type(8)));
typedef short s16x8 __attribute__((ext_vector_type(8)));
typedef float f32x4 __attribute__((ext_vector_type(4)));

#define MFMA(a, b, c) __builtin_amdgcn_mfma_f32_16x16x32_bf16( \
    __builtin_bit_cast(bf16x8, a), __builtin_bit_cast(bf16x8, b), c, 0, 0, 0)

__device__ __forceinline__ unsigned short f2bf(float x) {
  unsigned int u = __builtin_bit_cast(unsigned int, x);
  u += 0x7FFFu + ((u >> 16) & 1u);   // RNE
  return (unsigned short)(u >> 16);
}
__device__ __forceinline__ float bf2f(unsigned short b) {
  unsigned int u = ((unsigned int)b) << 16;
  return __builtin_bit_cast(float, u);
}

// ---------------- fp32 -> bf16 convert (single tensor) ----------------
__global__ __launch_bounds__(256) void f32_to_bf16(const float* __restrict__ in,
                                                   unsigned short* __restrict__ out, int n4) {
  int i = blockIdx.x * 256 + threadIdx.x;
  if (i < n4) {
    float4 v = ((const float4*)in)[i];
    ushort4 o;
    o.x = f2bf(v.x); o.y = f2bf(v.y); o.z = f2bf(v.z); o.w = f2bf(v.w);
    ((ushort4*)out)[i] = o;
  }
}

// ---------------- fused convert of the 5 pre-attention tensors ----------------
// float4-index ranges (cumulative): x 1048576 | wq_a 524288 | wq_b 1048576 |
// wkv 131072 | wo_a 524288  => total 3276800 (grid 12800 x 256)
__global__ __launch_bounds__(256) void conv5(
    const float* __restrict__ x, const float* __restrict__ wqa,
    const float* __restrict__ wqb, const float* __restrict__ wkv,
    const float* __restrict__ woa,
    unsigned short* __restrict__ xo, unsigned short* __restrict__ wqao,
    unsigned short* __restrict__ wqbo, unsigned short* __restrict__ wkvo,
    unsigned short* __restrict__ woao) {
  int i = blockIdx.x * 256 + threadIdx.x;
  const float* src; unsigned short* dst; int off;
  if (i < 1048576)      { src = x;   dst = xo;   off = i; }
  else if (i < 1572864) { src = wqa; dst = wqao; off = i - 1048576; }
  else if (i < 2621440) { src = wqb; dst = wqbo; off = i - 1572864; }
  else if (i < 2752512) { src = wkv; dst = wkvo; off = i - 2621440; }
  else                  { src = woa; dst = woao; off = i - 2752512; }
  float4 v = ((const float4*)src)[off];
  ushort4 o;
  o.x = f2bf(v.x); o.y = f2bf(v.y); o.z = f2bf(v.z); o.w = f2bf(v.w);
  ((ushort4*)dst)[off] = o;
}

// ---------------- bf16 MFMA GEMM: C[M,N] = A[M,K] @ B[N,K]^T ----------------
__global__ __launch_bounds__(256, 2) void gemm_bf16(
    const unsigned short* __restrict__ A, const unsigned short* __restrict__ B,
    void* __restrict__ Cv, int K, int lda, int ldb, int ldc,
    long aoffz, long boffz, long coffz, int store_bf) {
  __shared__ __align__(16) unsigned short As[128 * 40];
  __shared__ __align__(16) unsigned short Bs[128 * 40];
  A += (size_t)blockIdx.z * aoffz;
  B += (size_t)blockIdx.z * boffz;
  const int tid = threadIdx.x;
  const int wave = tid >> 6, lane = tid & 63;
  const int col = lane & 15, grp = lane >> 4;
  const int wm = wave >> 1, wn = wave & 1;
  const int m0 = blockIdx.y * 128, n0 = blockIdx.x * 128;

  f32x4 acc[4][4];
#pragma unroll
  for (int i = 0; i < 4; ++i)
#pragma unroll
    for (int j = 0; j < 4; ++j) acc[i][j] = (f32x4){0.f, 0.f, 0.f, 0.f};

  for (int k0 = 0; k0 < K; k0 += 32) {
#pragma unroll
    for (int u = 0; u < 2; ++u) {
      int lin = u * 256 + tid;
      int r = lin >> 2, c8 = (lin & 3) * 8;
      *(s16x8*)&As[r * 40 + c8] = *(const s16x8*)(A + (size_t)(m0 + r) * lda + k0 + c8);
      *(s16x8*)&Bs[r * 40 + c8] = *(const s16x8*)(B + (size_t)(n0 + r) * ldb + k0 + c8);
    }
    __syncthreads();
    s16x8 a[4], b[4];
#pragma unroll
    for (int i = 0; i < 4; ++i)
      a[i] = *(const s16x8*)&As[(wm * 64 + i * 16 + col) * 40 + grp * 8];
#pragma unroll
    for (int j = 0; j < 4; ++j)
      b[j] = *(const s16x8*)&Bs[(wn * 64 + j * 16 + col) * 40 + grp * 8];
#pragma unroll
    for (int i = 0; i < 4; ++i)
#pragma unroll
      for (int j = 0; j < 4; ++j)
        acc[i][j] = MFMA(a[i], b[j], acc[i][j]);
    __syncthreads();
  }

  if (store_bf) {
    unsigned short* C = (unsigned short*)Cv + (size_t)blockIdx.z * coffz;
#pragma unroll
    for (int i = 0; i < 4; ++i)
#pragma unroll
      for (int j = 0; j < 4; ++j)
#pragma unroll
        for (int r = 0; r < 4; ++r)
          C[(size_t)(m0 + wm * 64 + i * 16 + grp * 4 + r) * ldc +
            n0 + wn * 64 + j * 16 + col] = f2bf(acc[i][j][r]);
  } else {
    float* C = (float*)Cv + (size_t)blockIdx.z * coffz;
#pragma unroll
    for (int i = 0; i < 4; ++i)
#pragma unroll
      for (int j = 0; j < 4; ++j)
#pragma unroll
        for (int r = 0; r < 4; ++r)
          C[(size_t)(m0 + wm * 64 + i * 16 + grp * 4 + r) * ldc +
            n0 + wn * 64 + j * 16 + col] = acc[i][j][r];
  }
}

// ---------------- RMSNorm (weighted) in-place on bf16 rows of length L ----------------
__global__ __launch_bounds__(256) void rmsnorm_bf_ip(unsigned short* __restrict__ x,
                                                     const float* __restrict__ w, int L) {
  int row = blockIdx.x;
  unsigned short* p = x + (size_t)row * L;
  __shared__ float red[256];
  float s = 0.f;
  for (int i = threadIdx.x; i < L; i += 256) { float v = bf2f(p[i]); s += v * v; }
  red[threadIdx.x] = s;
  __syncthreads();
  for (int off = 128; off > 0; off >>= 1) {
    if (threadIdx.x < off) red[threadIdx.x] += red[threadIdx.x + off];
    __syncthreads();
  }
  float r = rsqrtf(red[0] / (float)L + EPS);
  for (int i = threadIdx.x; i < L; i += 256) p[i] = f2bf(bf2f(p[i]) * r * w[i]);
}

// ---------------- Q per-head RMS (no weight) + RoPE, in-place bf16 ----------------
__global__ __launch_bounds__(256) void qnorm_rope_ip(unsigned short* __restrict__ q,
                                                     const float* __restrict__ freqs) {
  int row = blockIdx.x;       // s*NH + h
  int s = row / NH;
  unsigned short* p = q + (size_t)row * HD;
  int d = threadIdx.x;
  float v = bf2f(p[d]);
  __shared__ float red[256];
  __shared__ float sm[256];
  red[d] = v * v;
  __syncthreads();
  for (int off = 128; off > 0; off >>= 1) {
    if (d < off) red[d] += red[d + off];
    __syncthreads();
  }
  float r = rsqrtf(red[0] / 256.0f + EPS);
  float nv = v * r;
  sm[d] = nv;
  __syncthreads();
  float outv = nv;
  if (d >= NOPE) {
    int j = (d - NOPE) >> 1;
    float f = freqs[(size_t)s * (NROT / 2) + j];
    float c = cosf(f), si = sinf(f);
    float x1 = sm[NOPE + 2 * j], x2 = sm[NOPE + 2 * j + 1];
    outv = ((d & 1) == 0) ? (x1 * c - x2 * si) : (x1 * si + x2 * c);
  }
  p[d] = f2bf(outv);
}

// ---------------- KV RMS (weighted) + RoPE, in-place bf16 + kvT global ----------------
__global__ __launch_bounds__(256) void kvnorm_rope_ip(unsigned short* __restrict__ kv,
                                                      const float* __restrict__ w,
                                                      const float* __restrict__ freqs,
                                                      unsigned short* __restrict__ kvT) {
  int s = blockIdx.x;
  unsigned short* p = kv + (size_t)s * HD;
  int d = threadIdx.x;
  float v = bf2f(p[d]);
  __shared__ float red[256];
  __shared__ float sm[256];
  red[d] = v * v;
  __syncthreads();
  for (int off = 128; off > 0; off >>= 1) {
    if (d < off) red[d] += red[d + off];
    __syncthreads();
  }
  float r = rsqrtf(red[0] / 256.0f + EPS);
  float nv = v * r * w[d];
  sm[d] = nv;
  __syncthreads();
  float outv = nv;
  if (d >= NOPE) {
    int j = (d - NOPE) >> 1;
    float f = freqs[(size_t)s * (NROT / 2) + j];
    float c = cosf(f), si = sinf(f);
    float x1 = sm[NOPE + 2 * j], x2 = sm[NOPE + 2 * j + 1];
    outv = ((d & 1) == 0) ? (x1 * c - x2 * si) : (x1 * si + x2 * c);
  }
  unsigned short ov = f2bf(outv);
  p[d] = ov;
  kvT[(size_t)d * S_LEN + s] = ov;   // transposed copy for PV B-frags
}

// ---------------- MFMA flash attention v5: key-chunk 64 ----------------
// R9 lesson: per-round fixed cost (barriers, shfl chains, expf) dominates at
// chunk 32. v5: 64-key chunks (2x MFMA/round, half the rounds), deferred
// l-reduction (per-lane partials, one final shfl-reduce), R9's register
// prefetch of all global traffic. No addressable arrays. LDS 43.5 KB.
__global__ __launch_bounds__(256, 2) void attn_mfma(
    const unsigned short* __restrict__ qbf,   // (S, NH*HD) bf16
    const unsigned short* __restrict__ kvbf,  // (S, HD) bf16
    const unsigned short* __restrict__ kvT,   // (HD, S) bf16
    const float* __restrict__ sink,
    const float* __restrict__ freqs,
    unsigned short* __restrict__ ob) {        // (S, NH*HD) bf16
  __shared__ __align__(16) unsigned short kv_s[64 * 264];  // [t][d]
  __shared__ __align__(16) unsigned short p_s[64 * 72];    // [row][t] (64 t + 8 pad)
  __shared__ float alpha_s[64];
  __shared__ float inv_s[64];

  const int tid = threadIdx.x;
  const int wave = tid >> 6, lane = tid & 63;
  const int col = lane & 15, grp = lane >> 4;
  const int q0 = (gridDim.x - 1 - blockIdx.x) * 64;   // big tiles first (LPT)
  const int h = blockIdx.y;
  const int qrow = q0 + wave * 16;

  // Q fragments: 8 named s16x8 regs (32 VGPRs)
  const unsigned short* qbase =
      qbf + (size_t)(qrow + col) * (NH * HD) + (size_t)h * HD + grp * 8;
#define QDECL(ko, nam) s16x8 nam = *(const s16x8*)(qbase + (ko) * 32);
  QDECL(0, qf0) QDECL(1, qf1) QDECL(2, qf2) QDECL(3, qf3)
  QDECL(4, qf4) QDECL(5, qf5) QDECL(6, qf6) QDECL(7, qf7)

  const f32x4 z4 = (f32x4){0.f, 0.f, 0.f, 0.f};
  float m0r = -1e30f, m1r = -1e30f, m2r = -1e30f, m3r = -1e30f;
  float lp0 = 0.f, lp1 = 0.f, lp2 = 0.f, lp3 = 0.f;   // per-lane partial l

#define FOR16(M) M(0,0,o00) M(0,1,o01) M(0,2,o02) M(0,3,o03) \
                 M(1,0,o10) M(1,1,o11) M(1,2,o12) M(1,3,o13) \
                 M(2,0,o20) M(2,1,o21) M(2,2,o22) M(2,3,o23) \
                 M(3,0,o30) M(3,1,o31) M(3,2,o32) M(3,3,o33)
#define DECLO(i, j, onam) f32x4 onam = z4;
  FOR16(DECLO)

  // Staging lane geometry: thread owns rows {tS+8k, k=0..7}, cols [ddS, ddS+8)
  const int tS = tid >> 5, ddS = (tid & 31) * 8;

  // Initial stage of chunk 0
  {
    const unsigned short* sb = kvbf + (size_t)tS * HD + ddS;
#pragma unroll
    for (int k = 0; k < 8; ++k)
      *(s16x8*)&kv_s[(tS + 8 * k) * 264 + ddS] = *(const s16x8*)(sb + (size_t)(8 * k) * HD);
  }

  const int nch = q0 / 64 + 1;
  for (int ch = 0; ch < nch; ++ch) {
    const int t0 = ch * 64;
    __syncthreads();   // kv_s(ch) ready; p_s/alpha_s(ch-1) consumed

    // ---- PREFETCH: next chunk staging (8) + this chunk's vf B-frags (8) ----
    const bool havest = (ch + 1 < nch);
    s16x8 st0 = {}, st1 = {}, st2 = {}, st3 = {}, st4 = {}, st5 = {}, st6 = {}, st7 = {};
    if (havest) {
      const unsigned short* sb = kvbf + (size_t)(t0 + 64 + tS) * HD + ddS;
      st0 = *(const s16x8*)(sb);
      st1 = *(const s16x8*)(sb + 8 * HD);
      st2 = *(const s16x8*)(sb + 16 * HD);
      st3 = *(const s16x8*)(sb + 24 * HD);
      st4 = *(const s16x8*)(sb + 32 * HD);
      st5 = *(const s16x8*)(sb + 40 * HD);
      st6 = *(const s16x8*)(sb + 48 * HD);
      st7 = *(const s16x8*)(sb + 56 * HD);
    }
    const unsigned short* vb = kvT + (size_t)(wave * 64 + col) * S_LEN + t0 + grp * 8;
    s16x8 vf00 = *(const s16x8*)(vb);
    s16x8 vf01 = *(const s16x8*)(vb + 32);
    s16x8 vf10 = *(const s16x8*)(vb + 16 * S_LEN);
    s16x8 vf11 = *(const s16x8*)(vb + 16 * S_LEN + 32);
    s16x8 vf20 = *(const s16x8*)(vb + 32 * S_LEN);
    s16x8 vf21 = *(const s16x8*)(vb + 32 * S_LEN + 32);
    s16x8 vf30 = *(const s16x8*)(vb + 48 * S_LEN);
    s16x8 vf31 = *(const s16x8*)(vb + 48 * S_LEN + 32);

    // ---- QK^T: four 16-key tiles ----
    f32x4 sA0 = z4, sA1 = z4, sA2 = z4, sA3 = z4;
#define QKS(ko, qf) { \
      s16x8 b0 = *(const s16x8*)&kv_s[col * 264 + (ko) * 32 + grp * 8]; \
      s16x8 b1 = *(const s16x8*)&kv_s[(16 + col) * 264 + (ko) * 32 + grp * 8]; \
      s16x8 b2 = *(const s16x8*)&kv_s[(32 + col) * 264 + (ko) * 32 + grp * 8]; \
      s16x8 b3 = *(const s16x8*)&kv_s[(48 + col) * 264 + (ko) * 32 + grp * 8]; \
      sA0 = MFMA(qf, b0, sA0); sA1 = MFMA(qf, b1, sA1); \
      sA2 = MFMA(qf, b2, sA2); sA3 = MFMA(qf, b3, sA3); }
    QKS(0, qf0) QKS(1, qf1) QKS(2, qf2) QKS(3, qf3)
    QKS(4, qf4) QKS(5, qf5) QKS(6, qf6) QKS(7, qf7)

    // ---- scale + causal mask ----
#define MASKR(r) { int sg = qrow + grp * 4 + (r); \
    sA0[r] = (t0 + col <= sg)      ? sA0[r] * SCALE : -1e30f; \
    sA1[r] = (t0 + 16 + col <= sg) ? sA1[r] * SCALE : -1e30f; \
    sA2[r] = (t0 + 32 + col <= sg) ? sA2[r] * SCALE : -1e30f; \
    sA3[r] = (t0 + 48 + col <= sg) ? sA3[r] * SCALE : -1e30f; }
    MASKR(0) MASKR(1) MASKR(2) MASKR(3)

    // ---- online softmax: row max -> alpha (l deferred) ----
    float a0, a1, a2, a3;
#define MAXR(r, mr, ar) { \
    float v = fmaxf(fmaxf(sA0[r], sA1[r]), fmaxf(sA2[r], sA3[r])); \
    v = fmaxf(v, __shfl_xor(v, 1)); v = fmaxf(v, __shfl_xor(v, 2)); \
    v = fmaxf(v, __shfl_xor(v, 4)); v = fmaxf(v, __shfl_xor(v, 8)); \
    float mn = fmaxf(mr, v); ar = __expf(mr - mn); mr = mn; }
    MAXR(0, m0r, a0) MAXR(1, m1r, a1) MAXR(2, m2r, a2) MAXR(3, m3r, a3)

    // ---- p, per-lane partial l, p_s writes ----
#define PROW(r, mr, lpr, ar) { \
    float p0 = __expf(sA0[r] - mr); float p1 = __expf(sA1[r] - mr); \
    float p2 = __expf(sA2[r] - mr); float p3 = __expf(sA3[r] - mr); \
    lpr = lpr * ar + (p0 + p1) + (p2 + p3); \
    int prow = (wave * 16 + grp * 4 + (r)) * 72; \
    p_s[prow + col] = f2bf(p0);      p_s[prow + 16 + col] = f2bf(p1); \
    p_s[prow + 32 + col] = f2bf(p2); p_s[prow + 48 + col] = f2bf(p3); }
    PROW(0, m0r, lp0, a0) PROW(1, m1r, lp1, a1) PROW(2, m2r, lp2, a2) PROW(3, m3r, lp3, a3)

    if (col == 0) {
      alpha_s[wave * 16 + grp * 4 + 0] = a0;
      alpha_s[wave * 16 + grp * 4 + 1] = a1;
      alpha_s[wave * 16 + grp * 4 + 2] = a2;
      alpha_s[wave * 16 + grp * 4 + 3] = a3;
    }
    __syncthreads();   // p_s/alpha_s ready; kv_s(ch) reads complete

    // ---- commit prefetched next chunk into kv_s ----
    if (havest) {
      *(s16x8*)&kv_s[tS * 264 + ddS]        = st0;
      *(s16x8*)&kv_s[(tS + 8) * 264 + ddS]  = st1;
      *(s16x8*)&kv_s[(tS + 16) * 264 + ddS] = st2;
      *(s16x8*)&kv_s[(tS + 24) * 264 + ddS] = st3;
      *(s16x8*)&kv_s[(tS + 32) * 264 + ddS] = st4;
      *(s16x8*)&kv_s[(tS + 40) * 264 + ddS] = st5;
      *(s16x8*)&kv_s[(tS + 48) * 264 + ddS] = st6;
      *(s16x8*)&kv_s[(tS + 56) * 264 + ddS] = st7;
    }

    // ---- rescale o-accs (alpha broadcast from LDS) ----
#define RESC(i) { f32x4 av = (f32x4){alpha_s[(i)*16 + grp*4 + 0], alpha_s[(i)*16 + grp*4 + 1], \
                                     alpha_s[(i)*16 + grp*4 + 2], alpha_s[(i)*16 + grp*4 + 3]}; \
    o##i##0 *= av; o##i##1 *= av; o##i##2 *= av; o##i##3 *= av; }
    RESC(0) RESC(1) RESC(2) RESC(3)

    // ---- PV: d-partition, K=64 in two halves, vf from prefetched regs ----
    s16x8 pf00 = *(const s16x8*)&p_s[(0 * 16 + col) * 72 + grp * 8];
    s16x8 pf01 = *(const s16x8*)&p_s[(0 * 16 + col) * 72 + 32 + grp * 8];
    s16x8 pf10 = *(const s16x8*)&p_s[(1 * 16 + col) * 72 + grp * 8];
    s16x8 pf11 = *(const s16x8*)&p_s[(1 * 16 + col) * 72 + 32 + grp * 8];
    s16x8 pf20 = *(const s16x8*)&p_s[(2 * 16 + col) * 72 + grp * 8];
    s16x8 pf21 = *(const s16x8*)&p_s[(2 * 16 + col) * 72 + 32 + grp * 8];
    s16x8 pf30 = *(const s16x8*)&p_s[(3 * 16 + col) * 72 + grp * 8];
    s16x8 pf31 = *(const s16x8*)&p_s[(3 * 16 + col) * 72 + 32 + grp * 8];
#define PVJ(j) { \
      o0##j = MFMA(pf00, vf##j##0, o0##j); o0##j = MFMA(pf01, vf##j##1, o0##j); \
      o1##j = MFMA(pf10, vf##j##0, o1##j); o1##j = MFMA(pf11, vf##j##1, o1##j); \
      o2##j = MFMA(pf20, vf##j##0, o2##j); o2##j = MFMA(pf21, vf##j##1, o2##j); \
      o3##j = MFMA(pf30, vf##j##0, o3##j); o3##j = MFMA(pf31, vf##j##1, o3##j); }
    PVJ(0) PVJ(1) PVJ(2) PVJ(3)
  }

  // ---- final l reduction + inv broadcast ----
  const float sk = sink[h];
  {
#define LRED(lpr) { lpr += __shfl_xor(lpr, 1); lpr += __shfl_xor(lpr, 2); \
                    lpr += __shfl_xor(lpr, 4); lpr += __shfl_xor(lpr, 8); }
    LRED(lp0) LRED(lp1) LRED(lp2) LRED(lp3)
    float i0 = 1.f / (lp0 + __expf(sk - m0r));
    float i1 = 1.f / (lp1 + __expf(sk - m1r));
    float i2 = 1.f / (lp2 + __expf(sk - m2r));
    float i3 = 1.f / (lp3 + __expf(sk - m3r));
    if (col == 0) {
      inv_s[wave * 16 + grp * 4 + 0] = i0;
      inv_s[wave * 16 + grp * 4 + 1] = i1;
      inv_s[wave * 16 + grp * 4 + 2] = i2;
      inv_s[wave * 16 + grp * 4 + 3] = i3;
    }
  }
  __syncthreads();

  // ---- epilogue: normalize, conj-RoPE (wave 3 owns dims 192..255), store ----
#define EPIJ(i, j, onam, ivv) { \
    float v0 = onam[0] * ivv[0]; float v1 = onam[1] * ivv[1]; \
    float v2 = onam[2] * ivv[2]; float v3 = onam[3] * ivv[3]; \
    if (wave == 3) { \
      int jr = ((j) * 16 + col) >> 1; \
      float f0 = freqs[(size_t)(q0 + (i) * 16 + grp * 4 + 0) * 32 + jr]; \
      float f1 = freqs[(size_t)(q0 + (i) * 16 + grp * 4 + 1) * 32 + jr]; \
      float f2 = freqs[(size_t)(q0 + (i) * 16 + grp * 4 + 2) * 32 + jr]; \
      float f3 = freqs[(size_t)(q0 + (i) * 16 + grp * 4 + 3) * 32 + jr]; \
      float p0 = __shfl_xor(v0, 1), p1 = __shfl_xor(v1, 1); \
      float p2 = __shfl_xor(v2, 1), p3 = __shfl_xor(v3, 1); \
      v0 = (col & 1) ? (v0 * cosf(f0) - p0 * sinf(f0)) : (v0 * cosf(f0) + p0 * sinf(f0)); \
      v1 = (col & 1) ? (v1 * cosf(f1) - p1 * sinf(f1)) : (v1 * cosf(f1) + p1 * sinf(f1)); \
      v2 = (col & 1) ? (v2 * cosf(f2) - p2 * sinf(f2)) : (v2 * cosf(f2) + p2 * sinf(f2)); \
      v3 = (col & 1) ? (v3 * cosf(f3) - p3 * sinf(f3)) : (v3 * cosf(f3) + p3 * sinf(f3)); \
    } \
    size_t obase = (size_t)(q0 + (i) * 16 + grp * 4) * (NH * HD) + (size_t)h * HD + \
                   wave * 64 + (j) * 16 + col; \
    ob[obase] = f2bf(v0); ob[obase + (NH * HD)] = f2bf(v1); \
    ob[obase + 2 * (NH * HD)] = f2bf(v2); ob[obase + 3 * (NH * HD)] = f2bf(v3); }
#define EPII(i) { \
    f32x4 ivv = (f32x4){inv_s[(i)*16 + grp*4 + 0], inv_s[(i)*16 + grp*4 + 1], \
                        inv_s[(i)*16 + grp*4 + 2], inv_s[(i)*16 + grp*4 + 3]}; \
    EPIJ(i, 0, o##i##0, ivv) EPIJ(i, 1, o##i##1, ivv) \
    EPIJ(i, 2, o##i##2, ivv) EPIJ(i, 3, o##i##3, ivv) }
  EPII(0) EPII(1) EPII(2) EPII(3)
}

extern "C" void kernel_launch(void* const* d_in, const int* in_sizes, int n_in,
                              void* d_out, int out_size, void* d_ws, size_t ws_size,
                              hipStream_t stream) {
  const float* x         = (const float*)d_in[0];
  const float* freqs     = (const float*)d_in[1];
  const float* wq_a      = (const float*)d_in[2];
  const float* q_norm_w  = (const float*)d_in[3];
  const float* wq_b      = (const float*)d_in[4];
  const float* wkv       = (const float*)d_in[5];
  const float* kv_norm_w = (const float*)d_in[6];
  const float* wo_a_w    = (const float*)d_in[7];
  const float* wo_b      = (const float*)d_in[8];
  const float* sink      = (const float*)d_in[9];
  float* out = (float*)d_out;

  // Workspace (byte offsets, 55 MB total):
  //  [0,4M)    qa_bf
  //  [4M,20M)  q_bf (G2 out -> attn). After attn: orb_bf [4M,12M), wob_bf [12M,20M)
  //  [20M,36M) o_bf (attn out); x_bf [20M,28M) dead before attn writes.
  //  [36M,40M) wqa_bf  [40M,48M) wqb_bf  [48M,49M) wkv_bf
  //  [49M,53M) woa_bf  [53M,54M) kv_bf  [54M,55M) kvT_bf
  char* ws = (char*)d_ws;
  const size_t MB = 1024 * 1024;
  unsigned short* qa_bf   = (unsigned short*)(ws + 0 * MB);
  unsigned short* q_bf    = (unsigned short*)(ws + 4 * MB);
  unsigned short* orb_bf  = (unsigned short*)(ws + 4 * MB);
  unsigned short* wob_bf  = (unsigned short*)(ws + 12 * MB);
  unsigned short* o_bf    = (unsigned short*)(ws + 20 * MB);
  unsigned short* x_bf    = (unsigned short*)(ws + 20 * MB);
  unsigned short* wqa_bf  = (unsigned short*)(ws + 36 * MB);
  unsigned short* wqb_bf  = (unsigned short*)(ws + 40 * MB);
  unsigned short* wkv_bf  = (unsigned short*)(ws + 48 * MB);
  unsigned short* woa_bf  = (unsigned short*)(ws + 49 * MB);
  unsigned short* kv_bf   = (unsigned short*)(ws + 53 * MB);
  unsigned short* kvT_bf  = (unsigned short*)(ws + 54 * MB);

  dim3 blk(256);

  // 0) fused fp32 -> bf16 conversion of the 5 pre-attention tensors
  conv5<<<dim3(12800), blk, 0, stream>>>(x, wq_a, wq_b, wkv, wo_a_w,
                                         x_bf, wqa_bf, wqb_bf, wkv_bf, woa_bf);

  // 1) qa = x @ wq_a^T  (2048x1024, K=2048) -> bf16
  gemm_bf16<<<dim3(QL / 128, S_LEN / 128, 1), blk, 0, stream>>>(
      x_bf, wqa_bf, qa_bf, HID, HID, HID, QL, 0, 0, 0, 1);
  // 2) RMS in-place
  rmsnorm_bf_ip<<<dim3(S_LEN), blk, 0, stream>>>(qa_bf, q_norm_w, QL);
  // 3) q = qa @ wq_b^T  (2048x4096, K=1024) -> bf16
  gemm_bf16<<<dim3(NH * HD / 128, S_LEN / 128, 1), blk, 0, stream>>>(
      qa_bf, wqb_bf, q_bf, QL, QL, QL, NH * HD, 0, 0, 0, 1);
  // 4) per-(s,h) RMS + RoPE in-place
  qnorm_rope_ip<<<dim3(S_LEN * NH), blk, 0, stream>>>(q_bf, freqs);
  // 5) kv = x @ wkv^T   (2048x256, K=2048) -> bf16
  gemm_bf16<<<dim3(HD / 128, S_LEN / 128, 1), blk, 0, stream>>>(
      x_bf, wkv_bf, kv_bf, HID, HID, HID, HD, 0, 0, 0, 1);
  // 6) RMS + RoPE in-place, also emit kvT
  kvnorm_rope_ip<<<dim3(S_LEN), blk, 0, stream>>>(kv_bf, kv_norm_w, freqs, kvT_bf);
  // 7) flash attention -> o_bf
  attn_mfma<<<dim3(S_LEN / 64, NH), blk, 0, stream>>>(q_bf, kv_bf, kvT_bf, sink, freqs, o_bf);
  // 7b) convert wo_b into [12M,20M) — q_bf dead after attention
  f32_to_bf16<<<dim3(4096), blk, 0, stream>>>(wo_b, wob_bf, 4 * 1024 * 1024 / 4);
  // 8) grouped projection via z-grid
  gemm_bf16<<<dim3(OR_ / 128, S_LEN / 128, NG), blk, 0, stream>>>(
      o_bf, woa_bf, orb_bf, HPG * HD, NH * HD, HPG * HD, NG * OR_,
      (long)(HPG * HD), (long)OR_ * (HPG * HD), (long)OR_, 1);
  // 9) out = orb @ wo_b^T (2048x2048, K=2048) -> fp32
  gemm_bf16<<<dim3(HID / 128, S_LEN / 128, 1), blk, 0, stream>>>(
      orb_bf, wob_bf, out, NG * OR_, NG * OR_, NG * OR_, HID, 0, 0, 0, 0);
}